// Round 1
// baseline (2555.882 us; speedup 1.0000x reference)
//
#include <hip/hip_runtime.h>
#include <hip/hip_bf16.h>

// LightGCN forward on MI355X.
// Pipeline per call (all on `stream`, graph-capture safe):
//  1) memset deg; histogram edges -> deg (int atomics)
//  2) dinv = rsqrt(deg)
//  3) single-block exclusive scan deg -> offs (CSR row offsets over N=users+items)
//  4) cursor = offs (d2d memcpyAsync); fill CSR col[] with 6M int fetch-adds
//  5) x0 = concat(Gu,Gi); bacc = x0[batch rows]
//  6) 3x { pull: x_new[n] = sum_{s in nbr(n)} dinv[n]*dinv[s]*x[s]  (no atomics);
//          bacc += x_new[batch rows]; swap(x, x_new) }
//  7) epilogue: proj = F[items] @ W^T + b, normalize, dots, out[b]

#define WAVE 64

__global__ void hist_kernel(const int* __restrict__ ue, const int* __restrict__ ie,
                            int* __restrict__ deg, int E, int nu) {
    int e = blockIdx.x * blockDim.x + threadIdx.x;
    if (e < E) {
        atomicAdd(&deg[ue[e]], 1);
        atomicAdd(&deg[nu + ie[e]], 1);
    }
}

__global__ void dinv_kernel(const int* __restrict__ deg, float* __restrict__ dinv, int N) {
    int n = blockIdx.x * blockDim.x + threadIdx.x;
    if (n < N) {
        int d = deg[n];
        dinv[n] = (d > 0) ? rsqrtf((float)d) : 0.0f;
    }
}

// Single-block exclusive scan: 1024 threads, each owns a contiguous segment.
__global__ __launch_bounds__(1024) void scan_kernel(const int* __restrict__ deg,
                                                    int* __restrict__ offs, int n) {
    __shared__ int wsum[16];
    const int T = 1024;
    int t = threadIdx.x;
    int per = (n + T - 1) / T;
    int s0 = t * per;
    int s1 = min(s0 + per, n);
    if (s0 > n) s0 = n;
    if (s1 < s0) s1 = s0;

    int local = 0;
    for (int i = s0; i < s1; ++i) local += deg[i];

    int lane = t & 63, w = t >> 6;
    int v = local;
    #pragma unroll
    for (int d = 1; d < 64; d <<= 1) {
        int o = __shfl_up(v, d, 64);
        if (lane >= d) v += o;
    }
    if (lane == 63) wsum[w] = v;
    __syncthreads();
    if (t == 0) {
        int r = 0;
        #pragma unroll
        for (int i = 0; i < 16; ++i) { int s = wsum[i]; wsum[i] = r; r += s; }
    }
    __syncthreads();
    int excl = (v - local) + wsum[w];

    int run = excl;
    for (int i = s0; i < s1; ++i) { offs[i] = run; run += deg[i]; }
    if (t == T - 1) offs[n] = run;  // grand total = 2E
}

__global__ void fill_kernel(const int* __restrict__ ue, const int* __restrict__ ie,
                            int* __restrict__ cursor, int* __restrict__ col, int E, int nu) {
    int e = blockIdx.x * blockDim.x + threadIdx.x;
    if (e < E) {
        int u = ue[e];
        int it = nu + ie[e];
        int p1 = atomicAdd(&cursor[it], 1);
        col[p1] = u;                // item node's neighbor list gets the user
        int p2 = atomicAdd(&cursor[u], 1);
        col[p2] = it;               // user node's neighbor list gets the item (global idx)
    }
}

__global__ void init_x_kernel(const float* __restrict__ Gu, const float* __restrict__ Gi,
                              float* __restrict__ x, int nuK, int totK) {
    int i = blockIdx.x * blockDim.x + threadIdx.x;
    if (i < totK) x[i] = (i < nuK) ? Gu[i] : Gi[i - nuK];
}

__global__ void init_bacc_kernel(const float* __restrict__ Gu, const float* __restrict__ Gi,
                                 const int* __restrict__ users, const int* __restrict__ items,
                                 float* __restrict__ baccU, float* __restrict__ baccI, int B) {
    int id = blockIdx.x * blockDim.x + threadIdx.x;
    if (id < B * WAVE) {
        int b = id >> 6, k = id & 63;
        baccU[id] = Gu[(size_t)users[b] * WAVE + k];
        baccI[id] = Gi[(size_t)items[b] * WAVE + k];
    }
}

// One wave per destination node; lane k owns column k of the 64-wide embedding.
__global__ __launch_bounds__(256) void pull_kernel(const float* __restrict__ x,
                                                   float* __restrict__ xn,
                                                   const int* __restrict__ offs,
                                                   const int* __restrict__ col,
                                                   const float* __restrict__ dinv, int N) {
    int wid = (blockIdx.x * blockDim.x + threadIdx.x) >> 6;
    int lane = threadIdx.x & 63;
    if (wid >= N) return;
    int s = offs[wid], e = offs[wid + 1];
    float dn = dinv[wid];
    float acc = 0.0f;
    int j = s;
    for (; j + 3 < e; j += 4) {
        int c0 = col[j], c1 = col[j + 1], c2 = col[j + 2], c3 = col[j + 3];
        float w0 = dinv[c0], w1 = dinv[c1], w2 = dinv[c2], w3 = dinv[c3];
        float v0 = x[(size_t)c0 * WAVE + lane];
        float v1 = x[(size_t)c1 * WAVE + lane];
        float v2 = x[(size_t)c2 * WAVE + lane];
        float v3 = x[(size_t)c3 * WAVE + lane];
        acc = fmaf(dn * w0, v0, acc);
        acc = fmaf(dn * w1, v1, acc);
        acc = fmaf(dn * w2, v2, acc);
        acc = fmaf(dn * w3, v3, acc);
    }
    for (; j < e; ++j) {
        int c = col[j];
        acc = fmaf(dn * dinv[c], x[(size_t)c * WAVE + lane], acc);
    }
    xn[(size_t)wid * WAVE + lane] = acc;
}

__global__ void gather_acc_kernel(const float* __restrict__ xn,
                                  const int* __restrict__ users, const int* __restrict__ items,
                                  float* __restrict__ baccU, float* __restrict__ baccI,
                                  int B, int nu) {
    int id = blockIdx.x * blockDim.x + threadIdx.x;
    if (id < B * WAVE) {
        int b = id >> 6, k = id & 63;
        baccU[id] += xn[(size_t)users[b] * WAVE + k];
        baccI[id] += xn[(size_t)(nu + items[b]) * WAVE + k];
    }
}

// One wave per batch element. F row staged in LDS; 64 dots vs proj_w (L2-resident).
__global__ __launch_bounds__(256) void final_kernel(const float* __restrict__ baccU,
                                                    const float* __restrict__ baccI,
                                                    const float* __restrict__ Tu,
                                                    const float* __restrict__ F,
                                                    const float* __restrict__ W,
                                                    const float* __restrict__ bvec,
                                                    const int* __restrict__ users,
                                                    const int* __restrict__ items,
                                                    float* __restrict__ out,
                                                    int B, int FEATn, float invL) {
    __shared__ float frow[4][1024];
    int lane = threadIdx.x & 63;
    int wq = threadIdx.x >> 6;
    int b = blockIdx.x * 4 + wq;
    if (b >= B) return;
    int u = users[b], it = items[b];

    const float* Fr = F + (size_t)it * FEATn;
    for (int t = lane; t < FEATn; t += WAVE) frow[wq][t] = Fr[t];
    // same-wave LDS RAW: compiler inserts lgkmcnt waits; no cross-wave sharing.

    float myp = 0.0f;
    for (int k = 0; k < 64; ++k) {
        const float* Wk = W + (size_t)k * FEATn;
        float p = 0.0f;
        for (int t = lane; t < FEATn; t += WAVE) p = fmaf(frow[wq][t], Wk[t], p);
        #pragma unroll
        for (int d = 32; d >= 1; d >>= 1) p += __shfl_xor(p, d, 64);
        if (lane == k) myp = p + bvec[k];
    }

    float q = myp * myp;
    #pragma unroll
    for (int d = 32; d >= 1; d >>= 1) q += __shfl_xor(q, d, 64);
    float inv = 1.0f / fmaxf(sqrtf(q), 1e-12f);
    float pi = myp * inv;

    float gu = baccU[(size_t)b * WAVE + lane] * invL;
    float gi = baccI[(size_t)b * WAVE + lane] * invL;
    float tu = Tu[(size_t)u * WAVE + lane];
    float sdot = fmaf(gu, gi, tu * pi);
    #pragma unroll
    for (int d = 32; d >= 1; d >>= 1) sdot += __shfl_xor(sdot, d, 64);
    if (lane == 0) out[b] = sdot;
}

extern "C" void kernel_launch(void* const* d_in, const int* in_sizes, int n_in,
                              void* d_out, int out_size, void* d_ws, size_t ws_size,
                              hipStream_t stream) {
    const float* Gu = (const float*)d_in[0];
    const float* Gi = (const float*)d_in[1];
    const float* Tu = (const float*)d_in[2];
    const float* F  = (const float*)d_in[3];
    const float* W  = (const float*)d_in[4];
    const float* bv = (const float*)d_in[5];
    const int* ue    = (const int*)d_in[6];
    const int* ie    = (const int*)d_in[7];
    const int* users = (const int*)d_in[8];
    const int* items = (const int*)d_in[9];
    float* out = (float*)d_out;

    const int K  = 64;
    const int nu = in_sizes[0] / K;
    const int ni = in_sizes[1] / K;
    const int N  = nu + ni;
    const int E  = in_sizes[6];
    const int B  = in_sizes[8];
    const int FEATn = in_sizes[3] / ni;
    const int NLAYERS = 3;

    // workspace carve-up (256B aligned)
    char* p = (char*)d_ws;
    auto alloc = [&](size_t bytes) -> void* {
        void* r = (void*)p;
        p += (bytes + 255) & ~(size_t)255;
        return r;
    };
    int*   deg    = (int*)  alloc((size_t)N * 4);
    float* dinv   = (float*)alloc((size_t)N * 4);
    int*   offs   = (int*)  alloc((size_t)(N + 1) * 4);
    int*   cursor = (int*)  alloc((size_t)N * 4);
    int*   col    = (int*)  alloc((size_t)2 * E * 4);
    float* x      = (float*)alloc((size_t)N * K * 4);
    float* xn     = (float*)alloc((size_t)N * K * 4);
    float* baccU  = (float*)alloc((size_t)B * K * 4);
    float* baccI  = (float*)alloc((size_t)B * K * 4);

    // 1) degrees
    hipMemsetAsync(deg, 0, (size_t)N * 4, stream);
    hist_kernel<<<(E + 255) / 256, 256, 0, stream>>>(ue, ie, deg, E, nu);
    // 2) dinv
    dinv_kernel<<<(N + 255) / 256, 256, 0, stream>>>(deg, dinv, N);
    // 3) CSR offsets
    scan_kernel<<<1, 1024, 0, stream>>>(deg, offs, N);
    // 4) CSR fill
    hipMemcpyAsync(cursor, offs, (size_t)N * 4, hipMemcpyDeviceToDevice, stream);
    fill_kernel<<<(E + 255) / 256, 256, 0, stream>>>(ue, ie, cursor, col, E, nu);
    // 5) x0 and batch accumulators
    init_x_kernel<<<((size_t)N * K + 255) / 256, 256, 0, stream>>>(Gu, Gi, x, nu * K, N * K);
    init_bacc_kernel<<<((size_t)B * K + 255) / 256, 256, 0, stream>>>(Gu, Gi, users, items,
                                                                      baccU, baccI, B);
    // 6) layers
    float* xa = x;
    float* xb = xn;
    for (int l = 0; l < NLAYERS; ++l) {
        int waves_per_block = 4;  // 256 threads
        int grid = (N + waves_per_block - 1) / waves_per_block;
        pull_kernel<<<grid, 256, 0, stream>>>(xa, xb, offs, col, dinv, N);
        gather_acc_kernel<<<((size_t)B * K + 255) / 256, 256, 0, stream>>>(xb, users, items,
                                                                           baccU, baccI, B, nu);
        float* t = xa; xa = xb; xb = t;
    }
    // 7) epilogue
    final_kernel<<<(B + 3) / 4, 256, 0, stream>>>(baccU, baccI, Tu, F, W, bv, users, items,
                                                  out, B, FEATn, 1.0f / (NLAYERS + 1));
}

// Round 2
// 2130.142 us; speedup vs baseline: 1.1999x; 1.1999x over previous
//
#include <hip/hip_runtime.h>
#include <hip/hip_bf16.h>

// LightGCN forward on MI355X.
// R2: (a) final_kernel replaced by register-tiled proj_out_kernel (fused GEMM +
//     normalize + dots) — R1 showed 642us at 0.8% HBM / 26% VALU, issue-bound
//     on per-wave W re-reads + shuffle storms.
//     (b) pull_kernel: cooperative 64-edge batches (one coalesced col load +
//     one dinv gather per 64 edges, broadcast via shfl) — kills the per-edge
//     dependent col->dinv->x load chain.
//     (c) float4 on the small elementwise kernels.

#define WAVE 64

__global__ void hist_kernel(const int* __restrict__ ue, const int* __restrict__ ie,
                            int* __restrict__ deg, int E, int nu) {
    int e = blockIdx.x * blockDim.x + threadIdx.x;
    if (e < E) {
        atomicAdd(&deg[ue[e]], 1);
        atomicAdd(&deg[nu + ie[e]], 1);
    }
}

__global__ void dinv_kernel(const int* __restrict__ deg, float* __restrict__ dinv, int N) {
    int n = blockIdx.x * blockDim.x + threadIdx.x;
    if (n < N) {
        int d = deg[n];
        dinv[n] = (d > 0) ? rsqrtf((float)d) : 0.0f;
    }
}

// Single-block exclusive scan: 1024 threads, each owns a contiguous segment.
__global__ __launch_bounds__(1024) void scan_kernel(const int* __restrict__ deg,
                                                    int* __restrict__ offs, int n) {
    __shared__ int wsum[16];
    const int T = 1024;
    int t = threadIdx.x;
    int per = (n + T - 1) / T;
    int s0 = t * per;
    int s1 = min(s0 + per, n);
    if (s0 > n) s0 = n;
    if (s1 < s0) s1 = s0;

    int local = 0;
    for (int i = s0; i < s1; ++i) local += deg[i];

    int lane = t & 63, w = t >> 6;
    int v = local;
    #pragma unroll
    for (int d = 1; d < 64; d <<= 1) {
        int o = __shfl_up(v, d, 64);
        if (lane >= d) v += o;
    }
    if (lane == 63) wsum[w] = v;
    __syncthreads();
    if (t == 0) {
        int r = 0;
        #pragma unroll
        for (int i = 0; i < 16; ++i) { int s = wsum[i]; wsum[i] = r; r += s; }
    }
    __syncthreads();
    int excl = (v - local) + wsum[w];

    int run = excl;
    for (int i = s0; i < s1; ++i) { offs[i] = run; run += deg[i]; }
    if (t == T - 1) offs[n] = run;  // grand total = 2E
}

__global__ void fill_kernel(const int* __restrict__ ue, const int* __restrict__ ie,
                            int* __restrict__ cursor, int* __restrict__ col, int E, int nu) {
    int e = blockIdx.x * blockDim.x + threadIdx.x;
    if (e < E) {
        int u = ue[e];
        int it = nu + ie[e];
        int p1 = atomicAdd(&cursor[it], 1);
        col[p1] = u;
        int p2 = atomicAdd(&cursor[u], 1);
        col[p2] = it;
    }
}

__global__ void init_x_kernel(const float* __restrict__ Gu, const float* __restrict__ Gi,
                              float* __restrict__ x, int nuK4, int totK4) {
    int i = blockIdx.x * blockDim.x + threadIdx.x;
    if (i < totK4) {
        const float4* src = (i < nuK4) ? (const float4*)Gu : (const float4*)Gi;
        int j = (i < nuK4) ? i : i - nuK4;
        ((float4*)x)[i] = src[j];
    }
}

__global__ void init_bacc_kernel(const float* __restrict__ Gu, const float* __restrict__ Gi,
                                 const int* __restrict__ users, const int* __restrict__ items,
                                 float* __restrict__ baccU, float* __restrict__ baccI, int B) {
    int id = blockIdx.x * blockDim.x + threadIdx.x;  // B*16 float4 slots
    if (id < B * 16) {
        int b = id >> 4, q = id & 15;
        ((float4*)baccU)[id] = ((const float4*)Gu)[(size_t)users[b] * 16 + q];
        ((float4*)baccI)[id] = ((const float4*)Gi)[(size_t)items[b] * 16 + q];
    }
}

// One wave per destination node; lane k owns column k of the 64-wide embedding.
// Cooperative edge batching: 64 edges' (col, dinv) loaded coalesced once,
// broadcast via shfl; only the x-row gather remains per edge.
__global__ __launch_bounds__(256) void pull_kernel(const float* __restrict__ x,
                                                   float* __restrict__ xn,
                                                   const int* __restrict__ offs,
                                                   const int* __restrict__ col,
                                                   const float* __restrict__ dinv, int N) {
    int wid = (blockIdx.x * blockDim.x + threadIdx.x) >> 6;
    int lane = threadIdx.x & 63;
    if (wid >= N) return;
    int s = offs[wid], e = offs[wid + 1];
    float acc = 0.0f;
    for (int base = s; base < e; base += 64) {
        int idx = base + lane;
        int c = (idx < e) ? col[idx] : 0;
        float w = (idx < e) ? dinv[c] : 0.0f;
        int n = min(64, e - base);
        int j = 0;
        for (; j + 4 <= n; j += 4) {
            int c0 = __shfl(c, j),     c1 = __shfl(c, j + 1);
            int c2 = __shfl(c, j + 2), c3 = __shfl(c, j + 3);
            float w0 = __shfl(w, j),     w1 = __shfl(w, j + 1);
            float w2 = __shfl(w, j + 2), w3 = __shfl(w, j + 3);
            float v0 = x[(size_t)c0 * WAVE + lane];
            float v1 = x[(size_t)c1 * WAVE + lane];
            float v2 = x[(size_t)c2 * WAVE + lane];
            float v3 = x[(size_t)c3 * WAVE + lane];
            acc = fmaf(w0, v0, acc);
            acc = fmaf(w1, v1, acc);
            acc = fmaf(w2, v2, acc);
            acc = fmaf(w3, v3, acc);
        }
        for (; j < n; ++j) {
            int cj = __shfl(c, j);
            float wj = __shfl(w, j);
            acc = fmaf(wj, x[(size_t)cj * WAVE + lane], acc);
        }
    }
    xn[(size_t)wid * WAVE + lane] = dinv[wid] * acc;
}

__global__ void gather_acc_kernel(const float* __restrict__ xn,
                                  const int* __restrict__ users, const int* __restrict__ items,
                                  float* __restrict__ baccU, float* __restrict__ baccI,
                                  int B, int nu) {
    int id = blockIdx.x * blockDim.x + threadIdx.x;  // B*16 float4 slots
    if (id < B * 16) {
        int b = id >> 4, q = id & 15;
        float4 a = ((float4*)baccU)[id];
        float4 v = ((const float4*)xn)[(size_t)users[b] * 16 + q];
        a.x += v.x; a.y += v.y; a.z += v.z; a.w += v.w;
        ((float4*)baccU)[id] = a;
        float4 c = ((float4*)baccI)[id];
        float4 d = ((const float4*)xn)[(size_t)(nu + items[b]) * 16 + q];
        c.x += d.x; c.y += d.y; c.z += d.z; c.w += d.w;
        ((float4*)baccI)[id] = c;
    }
}

// Fused projection GEMM + normalize + final dots.
// Grid: B/32 blocks of 256 threads. Thread tile: 2 rows x 4 cols.
// c0 = (tid%16)*4 (16 col-groups cover K=64), r0 = (tid/16)*2 (32 rows/block).
// F rows and W rows stream from global (L2/L3); no LDS, no barriers.
__global__ __launch_bounds__(256) void proj_out_kernel(const float* __restrict__ baccU,
                                                       const float* __restrict__ baccI,
                                                       const float* __restrict__ Tu,
                                                       const float* __restrict__ F,
                                                       const float* __restrict__ W,
                                                       const float* __restrict__ bvec,
                                                       const int* __restrict__ users,
                                                       const int* __restrict__ items,
                                                       float* __restrict__ out,
                                                       int B, float invL) {
    const int FEATn = 1024;
    int tid = threadIdx.x;
    int c0 = (tid & 15) * 4;
    int rl = (tid >> 4) * 2;
    int r0 = blockIdx.x * 32 + rl;
    if (r0 >= B) return;

    int it0 = items[r0], it1 = items[r0 + 1];
    const float4* F0 = (const float4*)(F + (size_t)it0 * FEATn);
    const float4* F1 = (const float4*)(F + (size_t)it1 * FEATn);
    const float4* W0 = (const float4*)(W + (size_t)(c0 + 0) * FEATn);
    const float4* W1 = (const float4*)(W + (size_t)(c0 + 1) * FEATn);
    const float4* W2 = (const float4*)(W + (size_t)(c0 + 2) * FEATn);
    const float4* W3 = (const float4*)(W + (size_t)(c0 + 3) * FEATn);

    float acc0[4] = {0, 0, 0, 0};
    float acc1[4] = {0, 0, 0, 0};
    #pragma unroll 2
    for (int q = 0; q < FEATn / 4; ++q) {
        float4 a0 = F0[q];
        float4 a1 = F1[q];
        float4 w0 = W0[q], w1 = W1[q], w2 = W2[q], w3 = W3[q];
        acc0[0] += a0.x * w0.x + a0.y * w0.y + a0.z * w0.z + a0.w * w0.w;
        acc0[1] += a0.x * w1.x + a0.y * w1.y + a0.z * w1.z + a0.w * w1.w;
        acc0[2] += a0.x * w2.x + a0.y * w2.y + a0.z * w2.z + a0.w * w2.w;
        acc0[3] += a0.x * w3.x + a0.y * w3.y + a0.z * w3.z + a0.w * w3.w;
        acc1[0] += a1.x * w0.x + a1.y * w0.y + a1.z * w0.z + a1.w * w0.w;
        acc1[1] += a1.x * w1.x + a1.y * w1.y + a1.z * w1.z + a1.w * w1.w;
        acc1[2] += a1.x * w2.x + a1.y * w2.y + a1.z * w2.z + a1.w * w2.w;
        acc1[3] += a1.x * w3.x + a1.y * w3.y + a1.z * w3.z + a1.w * w3.w;
    }

    float4 bb = *(const float4*)(bvec + c0);
    float pb0[4] = {acc0[0] + bb.x, acc0[1] + bb.y, acc0[2] + bb.z, acc0[3] + bb.w};
    float pb1[4] = {acc1[0] + bb.x, acc1[1] + bb.y, acc1[2] + bb.z, acc1[3] + bb.w};

    // per-row squared norm, reduced over the 16-lane col groups
    float s0 = pb0[0] * pb0[0] + pb0[1] * pb0[1] + pb0[2] * pb0[2] + pb0[3] * pb0[3];
    float s1 = pb1[0] * pb1[0] + pb1[1] * pb1[1] + pb1[2] * pb1[2] + pb1[3] * pb1[3];
    #pragma unroll
    for (int d = 1; d < 16; d <<= 1) {
        s0 += __shfl_xor(s0, d, 64);
        s1 += __shfl_xor(s1, d, 64);
    }
    float inv0 = 1.0f / fmaxf(sqrtf(s0), 1e-12f);
    float inv1 = 1.0f / fmaxf(sqrtf(s1), 1e-12f);

    int u0 = users[r0], u1 = users[r0 + 1];
    float4 tu0 = *(const float4*)(Tu + (size_t)u0 * WAVE + c0);
    float4 tu1 = *(const float4*)(Tu + (size_t)u1 * WAVE + c0);
    float4 gu0 = *(const float4*)(baccU + (size_t)r0 * WAVE + c0);
    float4 gu1 = *(const float4*)(baccU + (size_t)(r0 + 1) * WAVE + c0);
    float4 gi0 = *(const float4*)(baccI + (size_t)r0 * WAVE + c0);
    float4 gi1 = *(const float4*)(baccI + (size_t)(r0 + 1) * WAVE + c0);
    float L2 = invL * invL;

    float d0 = L2 * (gu0.x * gi0.x + gu0.y * gi0.y + gu0.z * gi0.z + gu0.w * gi0.w)
             + inv0 * (tu0.x * pb0[0] + tu0.y * pb0[1] + tu0.z * pb0[2] + tu0.w * pb0[3]);
    float d1 = L2 * (gu1.x * gi1.x + gu1.y * gi1.y + gu1.z * gi1.z + gu1.w * gi1.w)
             + inv1 * (tu1.x * pb1[0] + tu1.y * pb1[1] + tu1.z * pb1[2] + tu1.w * pb1[3]);
    #pragma unroll
    for (int d = 1; d < 16; d <<= 1) {
        d0 += __shfl_xor(d0, d, 64);
        d1 += __shfl_xor(d1, d, 64);
    }
    if ((tid & 15) == 0) {
        out[r0] = d0;
        out[r0 + 1] = d1;
    }
}

extern "C" void kernel_launch(void* const* d_in, const int* in_sizes, int n_in,
                              void* d_out, int out_size, void* d_ws, size_t ws_size,
                              hipStream_t stream) {
    const float* Gu = (const float*)d_in[0];
    const float* Gi = (const float*)d_in[1];
    const float* Tu = (const float*)d_in[2];
    const float* F  = (const float*)d_in[3];
    const float* W  = (const float*)d_in[4];
    const float* bv = (const float*)d_in[5];
    const int* ue    = (const int*)d_in[6];
    const int* ie    = (const int*)d_in[7];
    const int* users = (const int*)d_in[8];
    const int* items = (const int*)d_in[9];
    float* out = (float*)d_out;

    const int K  = 64;
    const int nu = in_sizes[0] / K;
    const int ni = in_sizes[1] / K;
    const int N  = nu + ni;
    const int E  = in_sizes[6];
    const int B  = in_sizes[8];
    const int NLAYERS = 3;

    char* p = (char*)d_ws;
    auto alloc = [&](size_t bytes) -> void* {
        void* r = (void*)p;
        p += (bytes + 255) & ~(size_t)255;
        return r;
    };
    int*   deg    = (int*)  alloc((size_t)N * 4);
    float* dinv   = (float*)alloc((size_t)N * 4);
    int*   offs   = (int*)  alloc((size_t)(N + 1) * 4);
    int*   cursor = (int*)  alloc((size_t)N * 4);
    int*   col    = (int*)  alloc((size_t)2 * E * 4);
    float* x      = (float*)alloc((size_t)N * K * 4);
    float* xn     = (float*)alloc((size_t)N * K * 4);
    float* baccU  = (float*)alloc((size_t)B * K * 4);
    float* baccI  = (float*)alloc((size_t)B * K * 4);

    hipMemsetAsync(deg, 0, (size_t)N * 4, stream);
    hist_kernel<<<(E + 255) / 256, 256, 0, stream>>>(ue, ie, deg, E, nu);
    dinv_kernel<<<(N + 255) / 256, 256, 0, stream>>>(deg, dinv, N);
    scan_kernel<<<1, 1024, 0, stream>>>(deg, offs, N);
    hipMemcpyAsync(cursor, offs, (size_t)N * 4, hipMemcpyDeviceToDevice, stream);
    fill_kernel<<<(E + 255) / 256, 256, 0, stream>>>(ue, ie, cursor, col, E, nu);

    int totQ = N * K / 4, nuQ = nu * K / 4;
    init_x_kernel<<<(totQ + 255) / 256, 256, 0, stream>>>(Gu, Gi, x, nuQ, totQ);
    init_bacc_kernel<<<(B * 16 + 255) / 256, 256, 0, stream>>>(Gu, Gi, users, items,
                                                               baccU, baccI, B);

    float* xa = x;
    float* xb = xn;
    for (int l = 0; l < NLAYERS; ++l) {
        int grid = (N + 3) / 4;  // 4 waves (nodes) per 256-thread block
        pull_kernel<<<grid, 256, 0, stream>>>(xa, xb, offs, col, dinv, N);
        gather_acc_kernel<<<(B * 16 + 255) / 256, 256, 0, stream>>>(xb, users, items,
                                                                    baccU, baccI, B, nu);
        float* t = xa; xa = xb; xb = t;
    }

    proj_out_kernel<<<(B + 31) / 32, 256, 0, stream>>>(baccU, baccI, Tu, F, W, bv,
                                                       users, items, out, B,
                                                       1.0f / (NLAYERS + 1));
}

// Round 3
// 1874.502 us; speedup vs baseline: 1.3635x; 1.1364x over previous
//
#include <hip/hip_runtime.h>
#include <hip/hip_bf16.h>

// LightGCN forward on MI355X.
// R3: (a) fill/hist: 4 edges/thread int4, grouped independent atomics->stores
//     (R2: fill 578us @ 0.2% VALU, 363MB random writes — latency-chain bound?)
//     (b) pull propagates z = dinv*x  =>  z_next[d] = dinv[d]^2 * sum z[c]:
//     pure adds in the inner loop, no per-edge dinv gather (-64B/edge).
//     gather_acc recovers x = sqrt(deg)*z at batch rows.
//     (c) last layer pulled only at ~29K unique batch nodes (flag+compact).

#define WAVE 64

__global__ void hist_kernel(const int* __restrict__ ue, const int* __restrict__ ie,
                            int* __restrict__ deg, int E, int nu) {
    int g = blockIdx.x * blockDim.x + threadIdx.x;
    int e0 = g * 4;
    if (e0 + 3 < E) {
        int4 u = *(const int4*)(ue + e0);
        int4 v = *(const int4*)(ie + e0);
        atomicAdd(&deg[u.x], 1); atomicAdd(&deg[u.y], 1);
        atomicAdd(&deg[u.z], 1); atomicAdd(&deg[u.w], 1);
        atomicAdd(&deg[nu + v.x], 1); atomicAdd(&deg[nu + v.y], 1);
        atomicAdd(&deg[nu + v.z], 1); atomicAdd(&deg[nu + v.w], 1);
    } else {
        for (int e = e0; e < E; ++e) {
            atomicAdd(&deg[ue[e]], 1);
            atomicAdd(&deg[nu + ie[e]], 1);
        }
    }
}

__global__ void dinv_kernel(const int* __restrict__ deg, float* __restrict__ dinv,
                            float* __restrict__ drt, int N) {
    int n = blockIdx.x * blockDim.x + threadIdx.x;
    if (n < N) {
        int d = deg[n];
        dinv[n] = (d > 0) ? rsqrtf((float)d) : 0.0f;
        drt[n]  = (d > 0) ? sqrtf((float)d)  : 0.0f;
    }
}

// Single-block exclusive scan: 1024 threads, each owns a contiguous segment.
__global__ __launch_bounds__(1024) void scan_kernel(const int* __restrict__ deg,
                                                    int* __restrict__ offs, int n) {
    __shared__ int wsum[16];
    const int T = 1024;
    const int per = 148;  // multiple of 4; 1024*148 >= 150000
    int t = threadIdx.x;
    int s0 = min(t * per, n);
    int s1 = min(s0 + per, n);

    int local = 0;
    int i = s0;
    for (; i + 3 < s1; i += 4) {
        int4 d = *(const int4*)(deg + i);
        local += d.x + d.y + d.z + d.w;
    }
    for (; i < s1; ++i) local += deg[i];

    int lane = t & 63, w = t >> 6;
    int v = local;
    #pragma unroll
    for (int d = 1; d < 64; d <<= 1) {
        int o = __shfl_up(v, d, 64);
        if (lane >= d) v += o;
    }
    if (lane == 63) wsum[w] = v;
    __syncthreads();
    if (t == 0) {
        int r = 0;
        #pragma unroll
        for (int k = 0; k < 16; ++k) { int s = wsum[k]; wsum[k] = r; r += s; }
    }
    __syncthreads();
    int excl = (v - local) + wsum[w];

    int run = excl;
    i = s0;
    for (; i + 3 < s1; i += 4) {
        int4 d = *(const int4*)(deg + i);
        int4 o;
        o.x = run; run += d.x;
        o.y = run; run += d.y;
        o.z = run; run += d.z;
        o.w = run; run += d.w;
        *(int4*)(offs + i) = o;
    }
    for (; i < s1; ++i) { offs[i] = run; run += deg[i]; }
    if (t == T - 1) offs[n] = run;  // grand total = 2E
}

__global__ void fill_kernel(const int* __restrict__ ue, const int* __restrict__ ie,
                            int* __restrict__ cursor, int* __restrict__ col, int E, int nu) {
    int g = blockIdx.x * blockDim.x + threadIdx.x;
    int e0 = g * 4;
    if (e0 + 3 < E) {
        int4 u = *(const int4*)(ue + e0);
        int4 v = *(const int4*)(ie + e0);
        // 8 independent atomics in flight, then 8 independent stores
        int p0 = atomicAdd(&cursor[nu + v.x], 1);
        int p1 = atomicAdd(&cursor[nu + v.y], 1);
        int p2 = atomicAdd(&cursor[nu + v.z], 1);
        int p3 = atomicAdd(&cursor[nu + v.w], 1);
        int q0 = atomicAdd(&cursor[u.x], 1);
        int q1 = atomicAdd(&cursor[u.y], 1);
        int q2 = atomicAdd(&cursor[u.z], 1);
        int q3 = atomicAdd(&cursor[u.w], 1);
        col[p0] = u.x; col[p1] = u.y; col[p2] = u.z; col[p3] = u.w;
        col[q0] = nu + v.x; col[q1] = nu + v.y; col[q2] = nu + v.z; col[q3] = nu + v.w;
    } else {
        for (int e = e0; e < E; ++e) {
            int u = ue[e];
            int it = nu + ie[e];
            int p1 = atomicAdd(&cursor[it], 1);
            int p2 = atomicAdd(&cursor[u], 1);
            col[p1] = u;
            col[p2] = it;
        }
    }
}

// z0 = dinv * concat(Gu, Gi)
__global__ void init_z_kernel(const float* __restrict__ Gu, const float* __restrict__ Gi,
                              const float* __restrict__ dinv,
                              float* __restrict__ z, int nuQ, int totQ) {
    int i = blockIdx.x * blockDim.x + threadIdx.x;  // float4 slots
    if (i < totQ) {
        const float4* src = (i < nuQ) ? (const float4*)Gu : (const float4*)Gi;
        int j = (i < nuQ) ? i : i - nuQ;
        float4 a = src[j];
        float w = dinv[i >> 4];
        a.x *= w; a.y *= w; a.z *= w; a.w *= w;
        ((float4*)z)[i] = a;
    }
}

__global__ void init_bacc_kernel(const float* __restrict__ Gu, const float* __restrict__ Gi,
                                 const int* __restrict__ users, const int* __restrict__ items,
                                 float* __restrict__ baccU, float* __restrict__ baccI, int B) {
    int id = blockIdx.x * blockDim.x + threadIdx.x;  // B*16 float4 slots
    if (id < B * 16) {
        int b = id >> 4, q = id & 15;
        ((float4*)baccU)[id] = ((const float4*)Gu)[(size_t)users[b] * 16 + q];
        ((float4*)baccI)[id] = ((const float4*)Gi)[(size_t)items[b] * 16 + q];
    }
}

// mark batch nodes (races benign), then compact into a row list
__global__ void mark_kernel(const int* __restrict__ users, const int* __restrict__ items,
                            int* __restrict__ flag, int B, int nu) {
    int b = blockIdx.x * blockDim.x + threadIdx.x;
    if (b < B) {
        flag[users[b]] = 1;
        flag[nu + items[b]] = 1;
    }
}

__global__ void compact_kernel(const int* __restrict__ flag, int* __restrict__ list,
                               int* __restrict__ cnt, int N) {
    int n = blockIdx.x * blockDim.x + threadIdx.x;
    if (n < N && flag[n]) {
        int pos = atomicAdd(cnt, 1);
        list[pos] = n;
    }
}

// One wave per destination row. z_next[r] = dinv[r]^2 * sum_{c in N(r)} z[c].
// Pure adds: col loaded coalesced per 64-edge batch, broadcast via shfl.
// rows==nullptr: r = wid over [0,N); else r = rows[wid] over [0,*n_ptr).
__global__ __launch_bounds__(256) void pull_kernel(const float* __restrict__ z,
                                                   float* __restrict__ zn,
                                                   const int* __restrict__ offs,
                                                   const int* __restrict__ col,
                                                   const float* __restrict__ dinv,
                                                   const int* __restrict__ rows,
                                                   const int* __restrict__ n_ptr, int N) {
    int wid = (blockIdx.x * blockDim.x + threadIdx.x) >> 6;
    int lane = threadIdx.x & 63;
    int nrows = rows ? *n_ptr : N;
    if (wid >= nrows) return;
    int r = rows ? rows[wid] : wid;
    int s = offs[r], e = offs[r + 1];
    float acc0 = 0.0f, acc1 = 0.0f;
    for (int base = s; base < e; base += 64) {
        int idx = base + lane;
        int c = (idx < e) ? col[idx] : 0;
        int n = min(64, e - base);
        int j = 0;
        for (; j + 4 <= n; j += 4) {
            int c0 = __shfl(c, j),     c1 = __shfl(c, j + 1);
            int c2 = __shfl(c, j + 2), c3 = __shfl(c, j + 3);
            float v0 = z[(size_t)c0 * WAVE + lane];
            float v1 = z[(size_t)c1 * WAVE + lane];
            float v2 = z[(size_t)c2 * WAVE + lane];
            float v3 = z[(size_t)c3 * WAVE + lane];
            acc0 += v0 + v1;
            acc1 += v2 + v3;
        }
        for (; j < n; ++j) {
            int cj = __shfl(c, j);
            acc0 += z[(size_t)cj * WAVE + lane];
        }
    }
    float w = dinv[r];
    zn[(size_t)r * WAVE + lane] = w * w * (acc0 + acc1);
}

// bacc += sqrt(deg) * z_layer at batch rows  (x = drt * z)
__global__ void gather_acc_kernel(const float* __restrict__ zn,
                                  const float* __restrict__ drt,
                                  const int* __restrict__ users, const int* __restrict__ items,
                                  float* __restrict__ baccU, float* __restrict__ baccI,
                                  int B, int nu) {
    int id = blockIdx.x * blockDim.x + threadIdx.x;  // B*16 float4 slots
    if (id < B * 16) {
        int b = id >> 4, q = id & 15;
        int u = users[b], it = nu + items[b];
        float wu = drt[u], wi = drt[it];
        float4 a = ((float4*)baccU)[id];
        float4 v = ((const float4*)zn)[(size_t)u * 16 + q];
        a.x += wu * v.x; a.y += wu * v.y; a.z += wu * v.z; a.w += wu * v.w;
        ((float4*)baccU)[id] = a;
        float4 c = ((float4*)baccI)[id];
        float4 d = ((const float4*)zn)[(size_t)it * 16 + q];
        c.x += wi * d.x; c.y += wi * d.y; c.z += wi * d.z; c.w += wi * d.w;
        ((float4*)baccI)[id] = c;
    }
}

// Fused projection GEMM + normalize + final dots.
// Grid: B/32 blocks of 256 threads. Thread tile: 2 rows x 4 cols.
__global__ __launch_bounds__(256) void proj_out_kernel(const float* __restrict__ baccU,
                                                       const float* __restrict__ baccI,
                                                       const float* __restrict__ Tu,
                                                       const float* __restrict__ F,
                                                       const float* __restrict__ W,
                                                       const float* __restrict__ bvec,
                                                       const int* __restrict__ users,
                                                       const int* __restrict__ items,
                                                       float* __restrict__ out,
                                                       int B, float invL) {
    const int FEATn = 1024;
    int tid = threadIdx.x;
    int c0 = (tid & 15) * 4;
    int rl = (tid >> 4) * 2;
    int r0 = blockIdx.x * 32 + rl;
    if (r0 >= B) return;

    int it0 = items[r0], it1 = items[r0 + 1];
    const float4* F0 = (const float4*)(F + (size_t)it0 * FEATn);
    const float4* F1 = (const float4*)(F + (size_t)it1 * FEATn);
    const float4* W0 = (const float4*)(W + (size_t)(c0 + 0) * FEATn);
    const float4* W1 = (const float4*)(W + (size_t)(c0 + 1) * FEATn);
    const float4* W2 = (const float4*)(W + (size_t)(c0 + 2) * FEATn);
    const float4* W3 = (const float4*)(W + (size_t)(c0 + 3) * FEATn);

    float acc0[4] = {0, 0, 0, 0};
    float acc1[4] = {0, 0, 0, 0};
    #pragma unroll 2
    for (int q = 0; q < FEATn / 4; ++q) {
        float4 a0 = F0[q];
        float4 a1 = F1[q];
        float4 w0 = W0[q], w1 = W1[q], w2 = W2[q], w3 = W3[q];
        acc0[0] += a0.x * w0.x + a0.y * w0.y + a0.z * w0.z + a0.w * w0.w;
        acc0[1] += a0.x * w1.x + a0.y * w1.y + a0.z * w1.z + a0.w * w1.w;
        acc0[2] += a0.x * w2.x + a0.y * w2.y + a0.z * w2.z + a0.w * w2.w;
        acc0[3] += a0.x * w3.x + a0.y * w3.y + a0.z * w3.z + a0.w * w3.w;
        acc1[0] += a1.x * w0.x + a1.y * w0.y + a1.z * w0.z + a1.w * w0.w;
        acc1[1] += a1.x * w1.x + a1.y * w1.y + a1.z * w1.z + a1.w * w1.w;
        acc1[2] += a1.x * w2.x + a1.y * w2.y + a1.z * w2.z + a1.w * w2.w;
        acc1[3] += a1.x * w3.x + a1.y * w3.y + a1.z * w3.z + a1.w * w3.w;
    }

    float4 bb = *(const float4*)(bvec + c0);
    float pb0[4] = {acc0[0] + bb.x, acc0[1] + bb.y, acc0[2] + bb.z, acc0[3] + bb.w};
    float pb1[4] = {acc1[0] + bb.x, acc1[1] + bb.y, acc1[2] + bb.z, acc1[3] + bb.w};

    float s0 = pb0[0] * pb0[0] + pb0[1] * pb0[1] + pb0[2] * pb0[2] + pb0[3] * pb0[3];
    float s1 = pb1[0] * pb1[0] + pb1[1] * pb1[1] + pb1[2] * pb1[2] + pb1[3] * pb1[3];
    #pragma unroll
    for (int d = 1; d < 16; d <<= 1) {
        s0 += __shfl_xor(s0, d, 64);
        s1 += __shfl_xor(s1, d, 64);
    }
    float inv0 = 1.0f / fmaxf(sqrtf(s0), 1e-12f);
    float inv1 = 1.0f / fmaxf(sqrtf(s1), 1e-12f);

    int u0 = users[r0], u1 = users[r0 + 1];
    float4 tu0 = *(const float4*)(Tu + (size_t)u0 * WAVE + c0);
    float4 tu1 = *(const float4*)(Tu + (size_t)u1 * WAVE + c0);
    float4 gu0 = *(const float4*)(baccU + (size_t)r0 * WAVE + c0);
    float4 gu1 = *(const float4*)(baccU + (size_t)(r0 + 1) * WAVE + c0);
    float4 gi0 = *(const float4*)(baccI + (size_t)r0 * WAVE + c0);
    float4 gi1 = *(const float4*)(baccI + (size_t)(r0 + 1) * WAVE + c0);
    float L2 = invL * invL;

    float d0 = L2 * (gu0.x * gi0.x + gu0.y * gi0.y + gu0.z * gi0.z + gu0.w * gi0.w)
             + inv0 * (tu0.x * pb0[0] + tu0.y * pb0[1] + tu0.z * pb0[2] + tu0.w * pb0[3]);
    float d1 = L2 * (gu1.x * gi1.x + gu1.y * gi1.y + gu1.z * gi1.z + gu1.w * gi1.w)
             + inv1 * (tu1.x * pb1[0] + tu1.y * pb1[1] + tu1.z * pb1[2] + tu1.w * pb1[3]);
    #pragma unroll
    for (int d = 1; d < 16; d <<= 1) {
        d0 += __shfl_xor(d0, d, 64);
        d1 += __shfl_xor(d1, d, 64);
    }
    if ((tid & 15) == 0) {
        out[r0] = d0;
        out[r0 + 1] = d1;
    }
}

extern "C" void kernel_launch(void* const* d_in, const int* in_sizes, int n_in,
                              void* d_out, int out_size, void* d_ws, size_t ws_size,
                              hipStream_t stream) {
    const float* Gu = (const float*)d_in[0];
    const float* Gi = (const float*)d_in[1];
    const float* Tu = (const float*)d_in[2];
    const float* F  = (const float*)d_in[3];
    const float* W  = (const float*)d_in[4];
    const float* bv = (const float*)d_in[5];
    const int* ue    = (const int*)d_in[6];
    const int* ie    = (const int*)d_in[7];
    const int* users = (const int*)d_in[8];
    const int* items = (const int*)d_in[9];
    float* out = (float*)d_out;

    const int K  = 64;
    const int nu = in_sizes[0] / K;
    const int ni = in_sizes[1] / K;
    const int N  = nu + ni;
    const int E  = in_sizes[6];
    const int B  = in_sizes[8];

    char* p = (char*)d_ws;
    auto alloc = [&](size_t bytes) -> void* {
        void* r = (void*)p;
        p += (bytes + 255) & ~(size_t)255;
        return r;
    };
    int*   deg    = (int*)  alloc((size_t)N * 4);
    float* dinv   = (float*)alloc((size_t)N * 4);
    float* drt    = (float*)alloc((size_t)N * 4);
    int*   offs   = (int*)  alloc((size_t)(N + 1) * 4);
    int*   cursor = (int*)  alloc((size_t)N * 4);   // reused as flag[] after fill
    int*   col    = (int*)  alloc((size_t)2 * E * 4);
    float* za     = (float*)alloc((size_t)N * K * 4);
    float* zb     = (float*)alloc((size_t)N * K * 4);
    float* baccU  = (float*)alloc((size_t)B * K * 4);
    float* baccI  = (float*)alloc((size_t)B * K * 4);
    int*   list   = (int*)  alloc((size_t)2 * B * 4);
    int*   cnt    = (int*)  alloc(256);

    // graph build
    hipMemsetAsync(deg, 0, (size_t)N * 4, stream);
    hist_kernel<<<(E / 4 + 255) / 256, 256, 0, stream>>>(ue, ie, deg, E, nu);
    dinv_kernel<<<(N + 255) / 256, 256, 0, stream>>>(deg, dinv, drt, N);
    scan_kernel<<<1, 1024, 0, stream>>>(deg, offs, N);
    hipMemcpyAsync(cursor, offs, (size_t)N * 4, hipMemcpyDeviceToDevice, stream);
    fill_kernel<<<(E / 4 + 255) / 256, 256, 0, stream>>>(ue, ie, cursor, col, E, nu);

    // batch-node list (cursor reused as flags)
    hipMemsetAsync(cursor, 0, (size_t)N * 4, stream);
    hipMemsetAsync(cnt, 0, 4, stream);
    mark_kernel<<<(B + 255) / 256, 256, 0, stream>>>(users, items, cursor, B, nu);
    compact_kernel<<<(N + 255) / 256, 256, 0, stream>>>(cursor, list, cnt, N);

    // init
    int totQ = N * K / 4, nuQ = nu * K / 4;
    init_z_kernel<<<(totQ + 255) / 256, 256, 0, stream>>>(Gu, Gi, dinv, za, nuQ, totQ);
    init_bacc_kernel<<<(B * 16 + 255) / 256, 256, 0, stream>>>(Gu, Gi, users, items,
                                                               baccU, baccI, B);

    // layer 1 (full)
    pull_kernel<<<(N + 3) / 4, 256, 0, stream>>>(za, zb, offs, col, dinv,
                                                 nullptr, nullptr, N);
    gather_acc_kernel<<<(B * 16 + 255) / 256, 256, 0, stream>>>(zb, drt, users, items,
                                                                baccU, baccI, B, nu);
    // layer 2 (full)
    pull_kernel<<<(N + 3) / 4, 256, 0, stream>>>(zb, za, offs, col, dinv,
                                                 nullptr, nullptr, N);
    gather_acc_kernel<<<(B * 16 + 255) / 256, 256, 0, stream>>>(za, drt, users, items,
                                                                baccU, baccI, B, nu);
    // layer 3 (sparse: only unique batch rows)
    pull_kernel<<<(2 * B + 3) / 4, 256, 0, stream>>>(za, zb, offs, col, dinv,
                                                     list, cnt, N);
    gather_acc_kernel<<<(B * 16 + 255) / 256, 256, 0, stream>>>(zb, drt, users, items,
                                                                baccU, baccI, B, nu);

    // epilogue
    proj_out_kernel<<<(B + 31) / 32, 256, 0, stream>>>(baccU, baccI, Tu, F, W, bv,
                                                       users, items, out, B, 0.25f);
}

// Round 4
// 1572.660 us; speedup vs baseline: 1.6252x; 1.1919x over previous
//
#include <hip/hip_runtime.h>
#include <hip/hip_bf16.h>

// LightGCN forward on MI355X.
// R4: hist/fill partitioned into 8 equal-edge dst-ranges, assigned to XCDs via
//     blockIdx%8 round-robin. R3 showed fill is HBM-write-amplification bound
//     (24MB payload -> 367MB HBM writes = 15x): col lines were dirtied by all
//     8 non-coherent XCD L2s. Now each col region is written by one XCD.
//     Edges are re-read 8x (L3-served, cheap). Same for hist's deg atomics.

#define WAVE 64

// --- range helpers -------------------------------------------------------
// hist ranges: node-id proportional (4 user ranges + 4 item ranges, equal E).
__device__ __forceinline__ int hist_range(int d, int nu, int unu, int uni) {
    return (d < nu) ? (d / unu) : 4 + ((d - nu) / uni);
}

__global__ __launch_bounds__(256) void hist_kernel(const int* __restrict__ ue,
                                                   const int* __restrict__ ie,
                                                   int* __restrict__ deg,
                                                   int E, int nu, int unu, int uni,
                                                   int gpc, int NG) {
    int r = blockIdx.x & 7;
    int chunk = blockIdx.x >> 3;
    int g0 = chunk * gpc;
    int g1 = min(g0 + gpc, NG);
    for (int g = g0 + (int)threadIdx.x; g < g1; g += 256) {
        int e0 = g * 4;
        if (e0 + 3 < E) {
            int4 u = *(const int4*)(ue + e0);
            int4 v = *(const int4*)(ie + e0);
            int du[4] = {u.x, u.y, u.z, u.w};
            int di[4] = {nu + v.x, nu + v.y, nu + v.z, nu + v.w};
            #pragma unroll
            for (int t = 0; t < 4; ++t) {
                if (hist_range(du[t], nu, unu, uni) == r) atomicAdd(&deg[du[t]], 1);
                if (hist_range(di[t], nu, unu, uni) == r) atomicAdd(&deg[di[t]], 1);
            }
        } else {
            for (int e = e0; e < E; ++e) {
                int du = ue[e], di = nu + ie[e];
                if (hist_range(du, nu, unu, uni) == r) atomicAdd(&deg[du], 1);
                if (hist_range(di, nu, unu, uni) == r) atomicAdd(&deg[di], 1);
            }
        }
    }
}

__global__ void dinv_kernel(const int* __restrict__ deg, float* __restrict__ dinv,
                            float* __restrict__ drt, int N) {
    int n = blockIdx.x * blockDim.x + threadIdx.x;
    if (n < N) {
        int d = deg[n];
        dinv[n] = (d > 0) ? rsqrtf((float)d) : 0.0f;
        drt[n]  = (d > 0) ? sqrtf((float)d)  : 0.0f;
    }
}

// Single-block exclusive scan: 1024 threads, each owns a contiguous segment.
__global__ __launch_bounds__(1024) void scan_kernel(const int* __restrict__ deg,
                                                    int* __restrict__ offs, int n) {
    __shared__ int wsum[16];
    const int T = 1024;
    const int per = 148;  // multiple of 4; 1024*148 >= 150000
    int t = threadIdx.x;
    int s0 = min(t * per, n);
    int s1 = min(s0 + per, n);

    int local = 0;
    int i = s0;
    for (; i + 3 < s1; i += 4) {
        int4 d = *(const int4*)(deg + i);
        local += d.x + d.y + d.z + d.w;
    }
    for (; i < s1; ++i) local += deg[i];

    int lane = t & 63, w = t >> 6;
    int v = local;
    #pragma unroll
    for (int d = 1; d < 64; d <<= 1) {
        int o = __shfl_up(v, d, 64);
        if (lane >= d) v += o;
    }
    if (lane == 63) wsum[w] = v;
    __syncthreads();
    if (t == 0) {
        int r = 0;
        #pragma unroll
        for (int k = 0; k < 16; ++k) { int s = wsum[k]; wsum[k] = r; r += s; }
    }
    __syncthreads();
    int excl = (v - local) + wsum[w];

    int run = excl;
    i = s0;
    for (; i + 3 < s1; i += 4) {
        int4 d = *(const int4*)(deg + i);
        int4 o;
        o.x = run; run += d.x;
        o.y = run; run += d.y;
        o.z = run; run += d.z;
        o.w = run; run += d.w;
        *(int4*)(offs + i) = o;
    }
    for (; i < s1; ++i) { offs[i] = run; run += deg[i]; }
    if (t == T - 1) offs[n] = run;  // grand total = 2E
}

// bounds[k] = first node n with offs[n] >= k*S, k in 1..7 (S = 2E/8).
__global__ void bounds_kernel(const int* __restrict__ offs, int* __restrict__ bounds,
                              int N, int S) {
    int n = blockIdx.x * blockDim.x + threadIdx.x;
    if (n >= 1 && n < N) {
        int lo = offs[n - 1], hi = offs[n];
        #pragma unroll
        for (int k = 1; k < 8; ++k) {
            int t = k * S;
            if (lo < t && hi >= t) bounds[k] = n;
        }
    }
}

// fill ranges: by CSR position via node-id bounds (equal-edge split).
__global__ __launch_bounds__(256) void fill_kernel(const int* __restrict__ ue,
                                                   const int* __restrict__ ie,
                                                   const int* __restrict__ bounds,
                                                   int* __restrict__ cursor,
                                                   int* __restrict__ col,
                                                   int E, int nu, int gpc, int NG) {
    int r = blockIdx.x & 7;
    int chunk = blockIdx.x >> 3;
    int b1 = bounds[1], b2 = bounds[2], b3 = bounds[3], b4 = bounds[4];
    int b5 = bounds[5], b6 = bounds[6], b7 = bounds[7];
    int g0 = chunk * gpc;
    int g1 = min(g0 + gpc, NG);
    for (int g = g0 + (int)threadIdx.x; g < g1; g += 256) {
        int e0 = g * 4;
        if (e0 + 3 < E) {
            int4 u = *(const int4*)(ue + e0);
            int4 v = *(const int4*)(ie + e0);
            int du[4] = {u.x, u.y, u.z, u.w};
            int di[4] = {nu + v.x, nu + v.y, nu + v.z, nu + v.w};
            #pragma unroll
            for (int t = 0; t < 4; ++t) {
                int d = di[t];
                int rr = (d >= b1) + (d >= b2) + (d >= b3) + (d >= b4)
                       + (d >= b5) + (d >= b6) + (d >= b7);
                if (rr == r) { int p = atomicAdd(&cursor[d], 1); col[p] = du[t]; }
                d = du[t];
                rr = (d >= b1) + (d >= b2) + (d >= b3) + (d >= b4)
                   + (d >= b5) + (d >= b6) + (d >= b7);
                if (rr == r) { int p = atomicAdd(&cursor[d], 1); col[p] = di[t]; }
            }
        } else {
            for (int e = e0; e < E; ++e) {
                int du = ue[e], di = nu + ie[e];
                int d = di;
                int rr = (d >= b1) + (d >= b2) + (d >= b3) + (d >= b4)
                       + (d >= b5) + (d >= b6) + (d >= b7);
                if (rr == r) { int p = atomicAdd(&cursor[d], 1); col[p] = du; }
                d = du;
                rr = (d >= b1) + (d >= b2) + (d >= b3) + (d >= b4)
                   + (d >= b5) + (d >= b6) + (d >= b7);
                if (rr == r) { int p = atomicAdd(&cursor[d], 1); col[p] = di; }
            }
        }
    }
}

// z0 = dinv * concat(Gu, Gi)
__global__ void init_z_kernel(const float* __restrict__ Gu, const float* __restrict__ Gi,
                              const float* __restrict__ dinv,
                              float* __restrict__ z, int nuQ, int totQ) {
    int i = blockIdx.x * blockDim.x + threadIdx.x;  // float4 slots
    if (i < totQ) {
        const float4* src = (i < nuQ) ? (const float4*)Gu : (const float4*)Gi;
        int j = (i < nuQ) ? i : i - nuQ;
        float4 a = src[j];
        float w = dinv[i >> 4];
        a.x *= w; a.y *= w; a.z *= w; a.w *= w;
        ((float4*)z)[i] = a;
    }
}

__global__ void init_bacc_kernel(const float* __restrict__ Gu, const float* __restrict__ Gi,
                                 const int* __restrict__ users, const int* __restrict__ items,
                                 float* __restrict__ baccU, float* __restrict__ baccI, int B) {
    int id = blockIdx.x * blockDim.x + threadIdx.x;  // B*16 float4 slots
    if (id < B * 16) {
        int b = id >> 4, q = id & 15;
        ((float4*)baccU)[id] = ((const float4*)Gu)[(size_t)users[b] * 16 + q];
        ((float4*)baccI)[id] = ((const float4*)Gi)[(size_t)items[b] * 16 + q];
    }
}

__global__ void mark_kernel(const int* __restrict__ users, const int* __restrict__ items,
                            int* __restrict__ flag, int B, int nu) {
    int b = blockIdx.x * blockDim.x + threadIdx.x;
    if (b < B) {
        flag[users[b]] = 1;
        flag[nu + items[b]] = 1;
    }
}

__global__ void compact_kernel(const int* __restrict__ flag, int* __restrict__ list,
                               int* __restrict__ cnt, int N) {
    int n = blockIdx.x * blockDim.x + threadIdx.x;
    if (n < N && flag[n]) {
        int pos = atomicAdd(cnt, 1);
        list[pos] = n;
    }
}

// One wave per destination row. z_next[r] = dinv[r]^2 * sum_{c in N(r)} z[c].
__global__ __launch_bounds__(256) void pull_kernel(const float* __restrict__ z,
                                                   float* __restrict__ zn,
                                                   const int* __restrict__ offs,
                                                   const int* __restrict__ col,
                                                   const float* __restrict__ dinv,
                                                   const int* __restrict__ rows,
                                                   const int* __restrict__ n_ptr, int N) {
    int wid = (blockIdx.x * blockDim.x + threadIdx.x) >> 6;
    int lane = threadIdx.x & 63;
    int nrows = rows ? *n_ptr : N;
    if (wid >= nrows) return;
    int r = rows ? rows[wid] : wid;
    int s = offs[r], e = offs[r + 1];
    float acc0 = 0.0f, acc1 = 0.0f;
    for (int base = s; base < e; base += 64) {
        int idx = base + lane;
        int c = (idx < e) ? col[idx] : 0;
        int n = min(64, e - base);
        int j = 0;
        for (; j + 4 <= n; j += 4) {
            int c0 = __shfl(c, j),     c1 = __shfl(c, j + 1);
            int c2 = __shfl(c, j + 2), c3 = __shfl(c, j + 3);
            float v0 = z[(size_t)c0 * WAVE + lane];
            float v1 = z[(size_t)c1 * WAVE + lane];
            float v2 = z[(size_t)c2 * WAVE + lane];
            float v3 = z[(size_t)c3 * WAVE + lane];
            acc0 += v0 + v1;
            acc1 += v2 + v3;
        }
        for (; j < n; ++j) {
            int cj = __shfl(c, j);
            acc0 += z[(size_t)cj * WAVE + lane];
        }
    }
    float w = dinv[r];
    zn[(size_t)r * WAVE + lane] = w * w * (acc0 + acc1);
}

// bacc += sqrt(deg) * z_layer at batch rows  (x = drt * z)
__global__ void gather_acc_kernel(const float* __restrict__ zn,
                                  const float* __restrict__ drt,
                                  const int* __restrict__ users, const int* __restrict__ items,
                                  float* __restrict__ baccU, float* __restrict__ baccI,
                                  int B, int nu) {
    int id = blockIdx.x * blockDim.x + threadIdx.x;  // B*16 float4 slots
    if (id < B * 16) {
        int b = id >> 4, q = id & 15;
        int u = users[b], it = nu + items[b];
        float wu = drt[u], wi = drt[it];
        float4 a = ((float4*)baccU)[id];
        float4 v = ((const float4*)zn)[(size_t)u * 16 + q];
        a.x += wu * v.x; a.y += wu * v.y; a.z += wu * v.z; a.w += wu * v.w;
        ((float4*)baccU)[id] = a;
        float4 c = ((float4*)baccI)[id];
        float4 d = ((const float4*)zn)[(size_t)it * 16 + q];
        c.x += wi * d.x; c.y += wi * d.y; c.z += wi * d.z; c.w += wi * d.w;
        ((float4*)baccI)[id] = c;
    }
}

// Fused projection GEMM + normalize + final dots. 2 rows x 4 cols per thread.
__global__ __launch_bounds__(256) void proj_out_kernel(const float* __restrict__ baccU,
                                                       const float* __restrict__ baccI,
                                                       const float* __restrict__ Tu,
                                                       const float* __restrict__ F,
                                                       const float* __restrict__ W,
                                                       const float* __restrict__ bvec,
                                                       const int* __restrict__ users,
                                                       const int* __restrict__ items,
                                                       float* __restrict__ out,
                                                       int B, float invL) {
    const int FEATn = 1024;
    int tid = threadIdx.x;
    int c0 = (tid & 15) * 4;
    int rl = (tid >> 4) * 2;
    int r0 = blockIdx.x * 32 + rl;
    if (r0 >= B) return;

    int it0 = items[r0], it1 = items[r0 + 1];
    const float4* F0 = (const float4*)(F + (size_t)it0 * FEATn);
    const float4* F1 = (const float4*)(F + (size_t)it1 * FEATn);
    const float4* W0 = (const float4*)(W + (size_t)(c0 + 0) * FEATn);
    const float4* W1 = (const float4*)(W + (size_t)(c0 + 1) * FEATn);
    const float4* W2 = (const float4*)(W + (size_t)(c0 + 2) * FEATn);
    const float4* W3 = (const float4*)(W + (size_t)(c0 + 3) * FEATn);

    float acc0[4] = {0, 0, 0, 0};
    float acc1[4] = {0, 0, 0, 0};
    #pragma unroll 2
    for (int q = 0; q < FEATn / 4; ++q) {
        float4 a0 = F0[q];
        float4 a1 = F1[q];
        float4 w0 = W0[q], w1 = W1[q], w2 = W2[q], w3 = W3[q];
        acc0[0] += a0.x * w0.x + a0.y * w0.y + a0.z * w0.z + a0.w * w0.w;
        acc0[1] += a0.x * w1.x + a0.y * w1.y + a0.z * w1.z + a0.w * w1.w;
        acc0[2] += a0.x * w2.x + a0.y * w2.y + a0.z * w2.z + a0.w * w2.w;
        acc0[3] += a0.x * w3.x + a0.y * w3.y + a0.z * w3.z + a0.w * w3.w;
        acc1[0] += a1.x * w0.x + a1.y * w0.y + a1.z * w0.z + a1.w * w0.w;
        acc1[1] += a1.x * w1.x + a1.y * w1.y + a1.z * w1.z + a1.w * w1.w;
        acc1[2] += a1.x * w2.x + a1.y * w2.y + a1.z * w2.z + a1.w * w2.w;
        acc1[3] += a1.x * w3.x + a1.y * w3.y + a1.z * w3.z + a1.w * w3.w;
    }

    float4 bb = *(const float4*)(bvec + c0);
    float pb0[4] = {acc0[0] + bb.x, acc0[1] + bb.y, acc0[2] + bb.z, acc0[3] + bb.w};
    float pb1[4] = {acc1[0] + bb.x, acc1[1] + bb.y, acc1[2] + bb.z, acc1[3] + bb.w};

    float s0 = pb0[0] * pb0[0] + pb0[1] * pb0[1] + pb0[2] * pb0[2] + pb0[3] * pb0[3];
    float s1 = pb1[0] * pb1[0] + pb1[1] * pb1[1] + pb1[2] * pb1[2] + pb1[3] * pb1[3];
    #pragma unroll
    for (int d = 1; d < 16; d <<= 1) {
        s0 += __shfl_xor(s0, d, 64);
        s1 += __shfl_xor(s1, d, 64);
    }
    float inv0 = 1.0f / fmaxf(sqrtf(s0), 1e-12f);
    float inv1 = 1.0f / fmaxf(sqrtf(s1), 1e-12f);

    int u0 = users[r0], u1 = users[r0 + 1];
    float4 tu0 = *(const float4*)(Tu + (size_t)u0 * WAVE + c0);
    float4 tu1 = *(const float4*)(Tu + (size_t)u1 * WAVE + c0);
    float4 gu0 = *(const float4*)(baccU + (size_t)r0 * WAVE + c0);
    float4 gu1 = *(const float4*)(baccU + (size_t)(r0 + 1) * WAVE + c0);
    float4 gi0 = *(const float4*)(baccI + (size_t)r0 * WAVE + c0);
    float4 gi1 = *(const float4*)(baccI + (size_t)(r0 + 1) * WAVE + c0);
    float L2 = invL * invL;

    float d0 = L2 * (gu0.x * gi0.x + gu0.y * gi0.y + gu0.z * gi0.z + gu0.w * gi0.w)
             + inv0 * (tu0.x * pb0[0] + tu0.y * pb0[1] + tu0.z * pb0[2] + tu0.w * pb0[3]);
    float d1 = L2 * (gu1.x * gi1.x + gu1.y * gi1.y + gu1.z * gi1.z + gu1.w * gi1.w)
             + inv1 * (tu1.x * pb1[0] + tu1.y * pb1[1] + tu1.z * pb1[2] + tu1.w * pb1[3]);
    #pragma unroll
    for (int d = 1; d < 16; d <<= 1) {
        d0 += __shfl_xor(d0, d, 64);
        d1 += __shfl_xor(d1, d, 64);
    }
    if ((tid & 15) == 0) {
        out[r0] = d0;
        out[r0 + 1] = d1;
    }
}

extern "C" void kernel_launch(void* const* d_in, const int* in_sizes, int n_in,
                              void* d_out, int out_size, void* d_ws, size_t ws_size,
                              hipStream_t stream) {
    const float* Gu = (const float*)d_in[0];
    const float* Gi = (const float*)d_in[1];
    const float* Tu = (const float*)d_in[2];
    const float* F  = (const float*)d_in[3];
    const float* W  = (const float*)d_in[4];
    const float* bv = (const float*)d_in[5];
    const int* ue    = (const int*)d_in[6];
    const int* ie    = (const int*)d_in[7];
    const int* users = (const int*)d_in[8];
    const int* items = (const int*)d_in[9];
    float* out = (float*)d_out;

    const int K  = 64;
    const int nu = in_sizes[0] / K;
    const int ni = in_sizes[1] / K;
    const int N  = nu + ni;
    const int E  = in_sizes[6];
    const int B  = in_sizes[8];

    char* p = (char*)d_ws;
    auto alloc = [&](size_t bytes) -> void* {
        void* r = (void*)p;
        p += (bytes + 255) & ~(size_t)255;
        return r;
    };
    int*   deg    = (int*)  alloc((size_t)N * 4);
    float* dinv   = (float*)alloc((size_t)N * 4);
    float* drt    = (float*)alloc((size_t)N * 4);
    int*   offs   = (int*)  alloc((size_t)(N + 1) * 4);
    int*   cursor = (int*)  alloc((size_t)N * 4);   // reused as flag[] after fill
    int*   col    = (int*)  alloc((size_t)2 * E * 4);
    float* za     = (float*)alloc((size_t)N * K * 4);
    float* zb     = (float*)alloc((size_t)N * K * 4);
    float* baccU  = (float*)alloc((size_t)B * K * 4);
    float* baccI  = (float*)alloc((size_t)B * K * 4);
    int*   list   = (int*)  alloc((size_t)2 * B * 4);
    int*   cnt    = (int*)  alloc(256);
    int*   bounds = (int*)  alloc(256);

    const int NG  = (E + 3) / 4;          // int4 edge groups
    const int CH  = 1024;                 // edge chunks per range
    const int gpc = (NG + CH - 1) / CH;   // groups per chunk
    const int grid8 = 8 * CH;
    const int unu = (nu + 3) / 4, uni = (ni + 3) / 4;

    // graph build
    hipMemsetAsync(deg, 0, (size_t)N * 4, stream);
    hist_kernel<<<grid8, 256, 0, stream>>>(ue, ie, deg, E, nu, unu, uni, gpc, NG);
    dinv_kernel<<<(N + 255) / 256, 256, 0, stream>>>(deg, dinv, drt, N);
    scan_kernel<<<1, 1024, 0, stream>>>(deg, offs, N);
    bounds_kernel<<<(N + 255) / 256, 256, 0, stream>>>(offs, bounds, N, (2 * E) / 8);
    hipMemcpyAsync(cursor, offs, (size_t)N * 4, hipMemcpyDeviceToDevice, stream);
    fill_kernel<<<grid8, 256, 0, stream>>>(ue, ie, bounds, cursor, col, E, nu, gpc, NG);

    // batch-node list (cursor reused as flags)
    hipMemsetAsync(cursor, 0, (size_t)N * 4, stream);
    hipMemsetAsync(cnt, 0, 4, stream);
    mark_kernel<<<(B + 255) / 256, 256, 0, stream>>>(users, items, cursor, B, nu);
    compact_kernel<<<(N + 255) / 256, 256, 0, stream>>>(cursor, list, cnt, N);

    // init
    int totQ = N * K / 4, nuQ = nu * K / 4;
    init_z_kernel<<<(totQ + 255) / 256, 256, 0, stream>>>(Gu, Gi, dinv, za, nuQ, totQ);
    init_bacc_kernel<<<(B * 16 + 255) / 256, 256, 0, stream>>>(Gu, Gi, users, items,
                                                               baccU, baccI, B);

    // layer 1 (full)
    pull_kernel<<<(N + 3) / 4, 256, 0, stream>>>(za, zb, offs, col, dinv,
                                                 nullptr, nullptr, N);
    gather_acc_kernel<<<(B * 16 + 255) / 256, 256, 0, stream>>>(zb, drt, users, items,
                                                                baccU, baccI, B, nu);
    // layer 2 (full)
    pull_kernel<<<(N + 3) / 4, 256, 0, stream>>>(zb, za, offs, col, dinv,
                                                 nullptr, nullptr, N);
    gather_acc_kernel<<<(B * 16 + 255) / 256, 256, 0, stream>>>(za, drt, users, items,
                                                                baccU, baccI, B, nu);
    // layer 3 (sparse: only unique batch rows)
    pull_kernel<<<(2 * B + 3) / 4, 256, 0, stream>>>(za, zb, offs, col, dinv,
                                                     list, cnt, N);
    gather_acc_kernel<<<(B * 16 + 255) / 256, 256, 0, stream>>>(zb, drt, users, items,
                                                                baccU, baccI, B, nu);

    // epilogue
    proj_out_kernel<<<(B + 31) / 32, 256, 0, stream>>>(baccU, baccI, Tu, F, W, bv,
                                                       users, items, out, B, 0.25f);
}

// Round 5
// 1340.054 us; speedup vs baseline: 1.9073x; 1.1736x over previous
//
#include <hip/hip_runtime.h>
#include <hip/hip_bf16.h>

// LightGCN forward on MI355X.
// R5: proj_out rewritten as LDS-tiled fp32 GEMM (64x64 block tile, 4x4 reg
//     tile/thread, double-buffered LDS, 1 barrier/K-tile). R4 showed it
//     latency-bound: 272us @ 1.9% HBM, 13% VALU, 23% occ — per-thread loads
//     had no reuse (W fetched 16x/block from L2) and no latency hiding.
//     Graph build (R4's XCD-partitioned hist/fill) unchanged.

#define WAVE 64

// --- range helpers -------------------------------------------------------
__device__ __forceinline__ int hist_range(int d, int nu, int unu, int uni) {
    return (d < nu) ? (d / unu) : 4 + ((d - nu) / uni);
}

__global__ __launch_bounds__(256) void hist_kernel(const int* __restrict__ ue,
                                                   const int* __restrict__ ie,
                                                   int* __restrict__ deg,
                                                   int E, int nu, int unu, int uni,
                                                   int gpc, int NG) {
    int r = blockIdx.x & 7;
    int chunk = blockIdx.x >> 3;
    int g0 = chunk * gpc;
    int g1 = min(g0 + gpc, NG);
    for (int g = g0 + (int)threadIdx.x; g < g1; g += 256) {
        int e0 = g * 4;
        if (e0 + 3 < E) {
            int4 u = *(const int4*)(ue + e0);
            int4 v = *(const int4*)(ie + e0);
            int du[4] = {u.x, u.y, u.z, u.w};
            int di[4] = {nu + v.x, nu + v.y, nu + v.z, nu + v.w};
            #pragma unroll
            for (int t = 0; t < 4; ++t) {
                if (hist_range(du[t], nu, unu, uni) == r) atomicAdd(&deg[du[t]], 1);
                if (hist_range(di[t], nu, unu, uni) == r) atomicAdd(&deg[di[t]], 1);
            }
        } else {
            for (int e = e0; e < E; ++e) {
                int du = ue[e], di = nu + ie[e];
                if (hist_range(du, nu, unu, uni) == r) atomicAdd(&deg[du], 1);
                if (hist_range(di, nu, unu, uni) == r) atomicAdd(&deg[di], 1);
            }
        }
    }
}

__global__ void dinv_kernel(const int* __restrict__ deg, float* __restrict__ dinv,
                            float* __restrict__ drt, int N) {
    int n = blockIdx.x * blockDim.x + threadIdx.x;
    if (n < N) {
        int d = deg[n];
        dinv[n] = (d > 0) ? rsqrtf((float)d) : 0.0f;
        drt[n]  = (d > 0) ? sqrtf((float)d)  : 0.0f;
    }
}

__global__ __launch_bounds__(1024) void scan_kernel(const int* __restrict__ deg,
                                                    int* __restrict__ offs, int n) {
    __shared__ int wsum[16];
    const int T = 1024;
    const int per = 148;  // multiple of 4; 1024*148 >= 150000
    int t = threadIdx.x;
    int s0 = min(t * per, n);
    int s1 = min(s0 + per, n);

    int local = 0;
    int i = s0;
    for (; i + 3 < s1; i += 4) {
        int4 d = *(const int4*)(deg + i);
        local += d.x + d.y + d.z + d.w;
    }
    for (; i < s1; ++i) local += deg[i];

    int lane = t & 63, w = t >> 6;
    int v = local;
    #pragma unroll
    for (int d = 1; d < 64; d <<= 1) {
        int o = __shfl_up(v, d, 64);
        if (lane >= d) v += o;
    }
    if (lane == 63) wsum[w] = v;
    __syncthreads();
    if (t == 0) {
        int r = 0;
        #pragma unroll
        for (int k = 0; k < 16; ++k) { int s = wsum[k]; wsum[k] = r; r += s; }
    }
    __syncthreads();
    int excl = (v - local) + wsum[w];

    int run = excl;
    i = s0;
    for (; i + 3 < s1; i += 4) {
        int4 d = *(const int4*)(deg + i);
        int4 o;
        o.x = run; run += d.x;
        o.y = run; run += d.y;
        o.z = run; run += d.z;
        o.w = run; run += d.w;
        *(int4*)(offs + i) = o;
    }
    for (; i < s1; ++i) { offs[i] = run; run += deg[i]; }
    if (t == T - 1) offs[n] = run;  // grand total = 2E
}

__global__ void bounds_kernel(const int* __restrict__ offs, int* __restrict__ bounds,
                              int N, int S) {
    int n = blockIdx.x * blockDim.x + threadIdx.x;
    if (n >= 1 && n < N) {
        int lo = offs[n - 1], hi = offs[n];
        #pragma unroll
        for (int k = 1; k < 8; ++k) {
            int t = k * S;
            if (lo < t && hi >= t) bounds[k] = n;
        }
    }
}

__global__ __launch_bounds__(256) void fill_kernel(const int* __restrict__ ue,
                                                   const int* __restrict__ ie,
                                                   const int* __restrict__ bounds,
                                                   int* __restrict__ cursor,
                                                   int* __restrict__ col,
                                                   int E, int nu, int gpc, int NG) {
    int r = blockIdx.x & 7;
    int chunk = blockIdx.x >> 3;
    int b1 = bounds[1], b2 = bounds[2], b3 = bounds[3], b4 = bounds[4];
    int b5 = bounds[5], b6 = bounds[6], b7 = bounds[7];
    int g0 = chunk * gpc;
    int g1 = min(g0 + gpc, NG);
    for (int g = g0 + (int)threadIdx.x; g < g1; g += 256) {
        int e0 = g * 4;
        if (e0 + 3 < E) {
            int4 u = *(const int4*)(ue + e0);
            int4 v = *(const int4*)(ie + e0);
            int du[4] = {u.x, u.y, u.z, u.w};
            int di[4] = {nu + v.x, nu + v.y, nu + v.z, nu + v.w};
            #pragma unroll
            for (int t = 0; t < 4; ++t) {
                int d = di[t];
                int rr = (d >= b1) + (d >= b2) + (d >= b3) + (d >= b4)
                       + (d >= b5) + (d >= b6) + (d >= b7);
                if (rr == r) { int p = atomicAdd(&cursor[d], 1); col[p] = du[t]; }
                d = du[t];
                rr = (d >= b1) + (d >= b2) + (d >= b3) + (d >= b4)
                   + (d >= b5) + (d >= b6) + (d >= b7);
                if (rr == r) { int p = atomicAdd(&cursor[d], 1); col[p] = di[t]; }
            }
        } else {
            for (int e = e0; e < E; ++e) {
                int du = ue[e], di = nu + ie[e];
                int d = di;
                int rr = (d >= b1) + (d >= b2) + (d >= b3) + (d >= b4)
                       + (d >= b5) + (d >= b6) + (d >= b7);
                if (rr == r) { int p = atomicAdd(&cursor[d], 1); col[p] = du; }
                d = du;
                rr = (d >= b1) + (d >= b2) + (d >= b3) + (d >= b4)
                   + (d >= b5) + (d >= b6) + (d >= b7);
                if (rr == r) { int p = atomicAdd(&cursor[d], 1); col[p] = di; }
            }
        }
    }
}

__global__ void init_z_kernel(const float* __restrict__ Gu, const float* __restrict__ Gi,
                              const float* __restrict__ dinv,
                              float* __restrict__ z, int nuQ, int totQ) {
    int i = blockIdx.x * blockDim.x + threadIdx.x;  // float4 slots
    if (i < totQ) {
        const float4* src = (i < nuQ) ? (const float4*)Gu : (const float4*)Gi;
        int j = (i < nuQ) ? i : i - nuQ;
        float4 a = src[j];
        float w = dinv[i >> 4];
        a.x *= w; a.y *= w; a.z *= w; a.w *= w;
        ((float4*)z)[i] = a;
    }
}

__global__ void init_bacc_kernel(const float* __restrict__ Gu, const float* __restrict__ Gi,
                                 const int* __restrict__ users, const int* __restrict__ items,
                                 float* __restrict__ baccU, float* __restrict__ baccI, int B) {
    int id = blockIdx.x * blockDim.x + threadIdx.x;  // B*16 float4 slots
    if (id < B * 16) {
        int b = id >> 4, q = id & 15;
        ((float4*)baccU)[id] = ((const float4*)Gu)[(size_t)users[b] * 16 + q];
        ((float4*)baccI)[id] = ((const float4*)Gi)[(size_t)items[b] * 16 + q];
    }
}

__global__ void mark_kernel(const int* __restrict__ users, const int* __restrict__ items,
                            int* __restrict__ flag, int B, int nu) {
    int b = blockIdx.x * blockDim.x + threadIdx.x;
    if (b < B) {
        flag[users[b]] = 1;
        flag[nu + items[b]] = 1;
    }
}

__global__ void compact_kernel(const int* __restrict__ flag, int* __restrict__ list,
                               int* __restrict__ cnt, int N) {
    int n = blockIdx.x * blockDim.x + threadIdx.x;
    if (n < N && flag[n]) {
        int pos = atomicAdd(cnt, 1);
        list[pos] = n;
    }
}

// One wave per destination row. z_next[r] = dinv[r]^2 * sum_{c in N(r)} z[c].
__global__ __launch_bounds__(256) void pull_kernel(const float* __restrict__ z,
                                                   float* __restrict__ zn,
                                                   const int* __restrict__ offs,
                                                   const int* __restrict__ col,
                                                   const float* __restrict__ dinv,
                                                   const int* __restrict__ rows,
                                                   const int* __restrict__ n_ptr, int N) {
    int wid = (blockIdx.x * blockDim.x + threadIdx.x) >> 6;
    int lane = threadIdx.x & 63;
    int nrows = rows ? *n_ptr : N;
    if (wid >= nrows) return;
    int r = rows ? rows[wid] : wid;
    int s = offs[r], e = offs[r + 1];
    float acc0 = 0.0f, acc1 = 0.0f;
    for (int base = s; base < e; base += 64) {
        int idx = base + lane;
        int c = (idx < e) ? col[idx] : 0;
        int n = min(64, e - base);
        int j = 0;
        for (; j + 4 <= n; j += 4) {
            int c0 = __shfl(c, j),     c1 = __shfl(c, j + 1);
            int c2 = __shfl(c, j + 2), c3 = __shfl(c, j + 3);
            float v0 = z[(size_t)c0 * WAVE + lane];
            float v1 = z[(size_t)c1 * WAVE + lane];
            float v2 = z[(size_t)c2 * WAVE + lane];
            float v3 = z[(size_t)c3 * WAVE + lane];
            acc0 += v0 + v1;
            acc1 += v2 + v3;
        }
        for (; j < n; ++j) {
            int cj = __shfl(c, j);
            acc0 += z[(size_t)cj * WAVE + lane];
        }
    }
    float w = dinv[r];
    zn[(size_t)r * WAVE + lane] = w * w * (acc0 + acc1);
}

__global__ void gather_acc_kernel(const float* __restrict__ zn,
                                  const float* __restrict__ drt,
                                  const int* __restrict__ users, const int* __restrict__ items,
                                  float* __restrict__ baccU, float* __restrict__ baccI,
                                  int B, int nu) {
    int id = blockIdx.x * blockDim.x + threadIdx.x;  // B*16 float4 slots
    if (id < B * 16) {
        int b = id >> 4, q = id & 15;
        int u = users[b], it = nu + items[b];
        float wu = drt[u], wi = drt[it];
        float4 a = ((float4*)baccU)[id];
        float4 v = ((const float4*)zn)[(size_t)u * 16 + q];
        a.x += wu * v.x; a.y += wu * v.y; a.z += wu * v.z; a.w += wu * v.w;
        ((float4*)baccU)[id] = a;
        float4 c = ((float4*)baccI)[id];
        float4 d = ((const float4*)zn)[(size_t)it * 16 + q];
        c.x += wi * d.x; c.y += wi * d.y; c.z += wi * d.z; c.w += wi * d.w;
        ((float4*)baccI)[id] = c;
    }
}

// LDS-tiled fp32 GEMM + fused epilogue.
// Block: 64 batch-rows x 64 outputs, 256 threads, 4x4 reg tile/thread.
// K loop: 32 tiles of 32 feats; double-buffered LDS, 1 barrier/tile.
// Ft[buf][kk][row], Wt[buf][kk][col] — b128 fragment reads (broadcast/2-way).
__global__ __launch_bounds__(256) void proj_out_kernel(const float* __restrict__ baccU,
                                                       const float* __restrict__ baccI,
                                                       const float* __restrict__ Tu,
                                                       const float* __restrict__ F,
                                                       const float* __restrict__ W,
                                                       const float* __restrict__ bvec,
                                                       const int* __restrict__ users,
                                                       const int* __restrict__ items,
                                                       float* __restrict__ out,
                                                       int B, float invL) {
    const int FEATn = 1024;
    __shared__ float Ft[2][32][64];
    __shared__ float Wt[2][32][64];

    int tid = threadIdx.x;
    int tx = tid & 15;        // col group (4 cols)
    int ty = tid >> 4;        // row group (4 rows)
    int r0 = blockIdx.x * 64;

    // staging assignment: thread loads 2 float4 of one F row + one W row
    int lr = tid >> 2;                       // 0..63
    int lq = tid & 3;                        // quad group: local kk 4*lq and 4*lq+16
    int frow = min(r0 + lr, B - 1);
    const float* Fp = F + (size_t)items[frow] * FEATn + lq * 4;
    const float* Wp = W + (size_t)lr * FEATn + lq * 4;

    float4 fa0 = *(const float4*)(Fp);
    float4 fa1 = *(const float4*)(Fp + 16);
    float4 wa0 = *(const float4*)(Wp);
    float4 wa1 = *(const float4*)(Wp + 16);

    float acc[4][4] = {};

    for (int kt = 0; kt < 32; ++kt) {
        int buf = kt & 1;
        #pragma unroll
        for (int i = 0; i < 4; ++i) {
            Ft[buf][lq * 4 + i][lr]      = ((const float*)&fa0)[i];
            Ft[buf][lq * 4 + 16 + i][lr] = ((const float*)&fa1)[i];
            Wt[buf][lq * 4 + i][lr]      = ((const float*)&wa0)[i];
            Wt[buf][lq * 4 + 16 + i][lr] = ((const float*)&wa1)[i];
        }
        __syncthreads();
        if (kt < 31) {
            const float* fp = Fp + (kt + 1) * 32;
            const float* wp = Wp + (kt + 1) * 32;
            fa0 = *(const float4*)(fp);
            fa1 = *(const float4*)(fp + 16);
            wa0 = *(const float4*)(wp);
            wa1 = *(const float4*)(wp + 16);
        }
        #pragma unroll 8
        for (int kk = 0; kk < 32; ++kk) {
            float4 a = *(const float4*)&Ft[buf][kk][ty * 4];
            float4 b = *(const float4*)&Wt[buf][kk][tx * 4];
            acc[0][0] = fmaf(a.x, b.x, acc[0][0]);
            acc[0][1] = fmaf(a.x, b.y, acc[0][1]);
            acc[0][2] = fmaf(a.x, b.z, acc[0][2]);
            acc[0][3] = fmaf(a.x, b.w, acc[0][3]);
            acc[1][0] = fmaf(a.y, b.x, acc[1][0]);
            acc[1][1] = fmaf(a.y, b.y, acc[1][1]);
            acc[1][2] = fmaf(a.y, b.z, acc[1][2]);
            acc[1][3] = fmaf(a.y, b.w, acc[1][3]);
            acc[2][0] = fmaf(a.z, b.x, acc[2][0]);
            acc[2][1] = fmaf(a.z, b.y, acc[2][1]);
            acc[2][2] = fmaf(a.z, b.z, acc[2][2]);
            acc[2][3] = fmaf(a.z, b.w, acc[2][3]);
            acc[3][0] = fmaf(a.w, b.x, acc[3][0]);
            acc[3][1] = fmaf(a.w, b.y, acc[3][1]);
            acc[3][2] = fmaf(a.w, b.z, acc[3][2]);
            acc[3][3] = fmaf(a.w, b.w, acc[3][3]);
        }
    }

    // fused epilogue: bias, row-normalize (16-lane groups hold a full row), dots
    float4 bb = *(const float4*)(bvec + tx * 4);
    float L2 = invL * invL;
    float res[4];
    #pragma unroll
    for (int r = 0; r < 4; ++r) {
        int gr = min(r0 + ty * 4 + r, B - 1);
        float pb0 = acc[r][0] + bb.x;
        float pb1 = acc[r][1] + bb.y;
        float pb2 = acc[r][2] + bb.z;
        float pb3 = acc[r][3] + bb.w;
        float s = pb0 * pb0 + pb1 * pb1 + pb2 * pb2 + pb3 * pb3;
        #pragma unroll
        for (int d = 1; d < 16; d <<= 1) s += __shfl_xor(s, d, 64);
        float inv = 1.0f / fmaxf(sqrtf(s), 1e-12f);
        int u = users[gr];
        float4 tu = *(const float4*)(Tu + (size_t)u * WAVE + tx * 4);
        float4 gu = *(const float4*)(baccU + (size_t)gr * WAVE + tx * 4);
        float4 gi = *(const float4*)(baccI + (size_t)gr * WAVE + tx * 4);
        float dsum = L2 * (gu.x * gi.x + gu.y * gi.y + gu.z * gi.z + gu.w * gi.w)
                   + inv * (tu.x * pb0 + tu.y * pb1 + tu.z * pb2 + tu.w * pb3);
        #pragma unroll
        for (int d = 1; d < 16; d <<= 1) dsum += __shfl_xor(dsum, d, 64);
        res[r] = dsum;
    }
    if (tx == 0) {
        #pragma unroll
        for (int r = 0; r < 4; ++r) {
            int gr = r0 + ty * 4 + r;
            if (gr < B) out[gr] = res[r];
        }
    }
}

extern "C" void kernel_launch(void* const* d_in, const int* in_sizes, int n_in,
                              void* d_out, int out_size, void* d_ws, size_t ws_size,
                              hipStream_t stream) {
    const float* Gu = (const float*)d_in[0];
    const float* Gi = (const float*)d_in[1];
    const float* Tu = (const float*)d_in[2];
    const float* F  = (const float*)d_in[3];
    const float* W  = (const float*)d_in[4];
    const float* bv = (const float*)d_in[5];
    const int* ue    = (const int*)d_in[6];
    const int* ie    = (const int*)d_in[7];
    const int* users = (const int*)d_in[8];
    const int* items = (const int*)d_in[9];
    float* out = (float*)d_out;

    const int K  = 64;
    const int nu = in_sizes[0] / K;
    const int ni = in_sizes[1] / K;
    const int N  = nu + ni;
    const int E  = in_sizes[6];
    const int B  = in_sizes[8];

    char* p = (char*)d_ws;
    auto alloc = [&](size_t bytes) -> void* {
        void* r = (void*)p;
        p += (bytes + 255) & ~(size_t)255;
        return r;
    };
    int*   deg    = (int*)  alloc((size_t)N * 4);
    float* dinv   = (float*)alloc((size_t)N * 4);
    float* drt    = (float*)alloc((size_t)N * 4);
    int*   offs   = (int*)  alloc((size_t)(N + 1) * 4);
    int*   cursor = (int*)  alloc((size_t)N * 4);   // reused as flag[] after fill
    int*   col    = (int*)  alloc((size_t)2 * E * 4);
    float* za     = (float*)alloc((size_t)N * K * 4);
    float* zb     = (float*)alloc((size_t)N * K * 4);
    float* baccU  = (float*)alloc((size_t)B * K * 4);
    float* baccI  = (float*)alloc((size_t)B * K * 4);
    int*   list   = (int*)  alloc((size_t)2 * B * 4);
    int*   cnt    = (int*)  alloc(256);
    int*   bounds = (int*)  alloc(256);

    const int NG  = (E + 3) / 4;          // int4 edge groups
    const int CH  = 1024;                 // edge chunks per range
    const int gpc = (NG + CH - 1) / CH;   // groups per chunk
    const int grid8 = 8 * CH;
    const int unu = (nu + 3) / 4, uni = (ni + 3) / 4;

    // graph build
    hipMemsetAsync(deg, 0, (size_t)N * 4, stream);
    hist_kernel<<<grid8, 256, 0, stream>>>(ue, ie, deg, E, nu, unu, uni, gpc, NG);
    dinv_kernel<<<(N + 255) / 256, 256, 0, stream>>>(deg, dinv, drt, N);
    scan_kernel<<<1, 1024, 0, stream>>>(deg, offs, N);
    bounds_kernel<<<(N + 255) / 256, 256, 0, stream>>>(offs, bounds, N, (2 * E) / 8);
    hipMemcpyAsync(cursor, offs, (size_t)N * 4, hipMemcpyDeviceToDevice, stream);
    fill_kernel<<<grid8, 256, 0, stream>>>(ue, ie, bounds, cursor, col, E, nu, gpc, NG);

    // batch-node list (cursor reused as flags)
    hipMemsetAsync(cursor, 0, (size_t)N * 4, stream);
    hipMemsetAsync(cnt, 0, 4, stream);
    mark_kernel<<<(B + 255) / 256, 256, 0, stream>>>(users, items, cursor, B, nu);
    compact_kernel<<<(N + 255) / 256, 256, 0, stream>>>(cursor, list, cnt, N);

    // init
    int totQ = N * K / 4, nuQ = nu * K / 4;
    init_z_kernel<<<(totQ + 255) / 256, 256, 0, stream>>>(Gu, Gi, dinv, za, nuQ, totQ);
    init_bacc_kernel<<<(B * 16 + 255) / 256, 256, 0, stream>>>(Gu, Gi, users, items,
                                                               baccU, baccI, B);

    // layer 1 (full)
    pull_kernel<<<(N + 3) / 4, 256, 0, stream>>>(za, zb, offs, col, dinv,
                                                 nullptr, nullptr, N);
    gather_acc_kernel<<<(B * 16 + 255) / 256, 256, 0, stream>>>(zb, drt, users, items,
                                                                baccU, baccI, B, nu);
    // layer 2 (full)
    pull_kernel<<<(N + 3) / 4, 256, 0, stream>>>(zb, za, offs, col, dinv,
                                                 nullptr, nullptr, N);
    gather_acc_kernel<<<(B * 16 + 255) / 256, 256, 0, stream>>>(za, drt, users, items,
                                                                baccU, baccI, B, nu);
    // layer 3 (sparse: only unique batch rows)
    pull_kernel<<<(2 * B + 3) / 4, 256, 0, stream>>>(za, zb, offs, col, dinv,
                                                     list, cnt, N);
    gather_acc_kernel<<<(B * 16 + 255) / 256, 256, 0, stream>>>(zb, drt, users, items,
                                                                baccU, baccI, B, nu);

    // epilogue: LDS-tiled GEMM + fused norm/dots
    proj_out_kernel<<<(B + 63) / 64, 256, 0, stream>>>(baccU, baccI, Tu, F, W, bv,
                                                       users, items, out, B, 0.25f);
}